// Round 5
// baseline (439.506 us; speedup 1.0000x reference)
//
#include <hip/hip_runtime.h>
#include <math.h>

// ---------------------------------------------------------------------------
// AGNNet: GAT-like 3-layer GNN. N=100000 nodes, E=800000 edges, HID=64.
// R5: layer = ONE fused kernel (gather Sum(alpha*h[src]) into LDS tile, then
// 64x64 GEMM, using linearity Sum a(hW+b) = (Sum a h)W + (Sum a)b, Sum a = 1).
// Layer 2 also fuses the 64x40 output GEMM (h3 never hits global).
// k_in_gemm: 128-node tile, K in two chunks -> 51 KB LDS, 3 blocks/CU.
// ---------------------------------------------------------------------------

#define HID 64
#define INC 128

// ---------------- CSR build ----------------
__global__ __launch_bounds__(256) void k_degree(
    const int* __restrict__ dst, int* __restrict__ deg, int E)
{
    int e = blockIdx.x * 256 + threadIdx.x;
    if (e < E) atomicAdd(deg + dst[e], 1);
}

__global__ __launch_bounds__(256) void k_scan1(
    const int* __restrict__ deg, int* __restrict__ rowptr,
    int* __restrict__ bsum, int n)
{
    __shared__ int sdata[256];
    const int t = threadIdx.x;
    const int i0 = blockIdx.x * 1024 + t * 4;
    int v[4];
    #pragma unroll
    for (int j = 0; j < 4; ++j) v[j] = (i0 + j < n) ? deg[i0 + j] : 0;
    int ts = v[0] + v[1] + v[2] + v[3];
    sdata[t] = ts;
    __syncthreads();
    for (int off = 1; off < 256; off <<= 1) {
        int add = (t >= off) ? sdata[t - off] : 0;
        __syncthreads();
        sdata[t] += add;
        __syncthreads();
    }
    int excl = sdata[t] - ts;
    int run = excl;
    #pragma unroll
    for (int j = 0; j < 4; ++j) {
        if (i0 + j < n) rowptr[i0 + j] = run;
        run += v[j];
    }
    if (t == 255) bsum[blockIdx.x] = sdata[255];
}

__global__ __launch_bounds__(128) void k_scan2(int* __restrict__ bsum, int B)
{
    __shared__ int sdata[128];
    const int t = threadIdx.x;
    int v = (t < B) ? bsum[t] : 0;
    sdata[t] = v;
    __syncthreads();
    for (int off = 1; off < 128; off <<= 1) {
        int add = (t >= off) ? sdata[t - off] : 0;
        __syncthreads();
        sdata[t] += add;
        __syncthreads();
    }
    if (t < B) bsum[t] = sdata[t] - v;
}

__global__ __launch_bounds__(256) void k_scan3(
    int* __restrict__ rowptr, int* __restrict__ cursor,
    const int* __restrict__ bsum, int n, int E)
{
    const int t = threadIdx.x;
    const int i0 = blockIdx.x * 1024 + t * 4;
    const int add = bsum[blockIdx.x];
    #pragma unroll
    for (int j = 0; j < 4; ++j) {
        int i = i0 + j;
        if (i < n) {
            int r = rowptr[i] + add;
            rowptr[i] = r;
            cursor[i] = r;
        }
    }
    if (blockIdx.x == 0 && t == 0) rowptr[n] = E;
}

__global__ __launch_bounds__(256) void k_place(
    const int* __restrict__ src, const int* __restrict__ dst,
    int* __restrict__ cursor, int* __restrict__ csr_src, int E)
{
    int e = blockIdx.x * 256 + threadIdx.x;
    if (e < E) {
        int slot = atomicAdd(cursor + dst[e], 1);
        csr_src[slot] = src[e];
    }
}

// ---------------- Input GEMM ----------------
// h0 = relu(x @ W_in + b_in), 128-node x 64-col tile, K chunked in 2x64.
// Fused reductions: delta=sum h0 (h0>=0), hwp=h0.wp, ai=h0.w_i, aj=h0.w_j
__global__ __launch_bounds__(256) void k_in_gemm(
    const float* __restrict__ x, const float* __restrict__ Win,
    const float* __restrict__ bin, const float* __restrict__ wp,
    const float* __restrict__ attw,
    float* __restrict__ h0, float* __restrict__ delta, float* __restrict__ hwp,
    float* __restrict__ ai, float* __restrict__ aj, int n)
{
    __shared__ float xs[128 * 68];    // 34.8 KB
    __shared__ float Ws[64 * 64];     // 16 KB (one K-chunk of W_in)
    const int t = threadIdx.x;
    const int node0 = blockIdx.x * 128;

    const int cx = t & 15;            // 4 output cols: cx*4..+3
    const int ry = t >> 4;            // 8 rows: ry + 16*i

    float acc[8][4];
    #pragma unroll
    for (int i = 0; i < 8; ++i)
        #pragma unroll
        for (int j = 0; j < 4; ++j) acc[i][j] = 0.f;

    for (int ch = 0; ch < 2; ++ch) {
        if (ch) __syncthreads();
        // stage x chunk: 128 rows x 64 cols
        #pragma unroll
        for (int p = 0; p < 8; ++p) {
            int c = t + p * 256;
            int row = c >> 4;
            int col = (c & 15) * 4;
            float4 v = make_float4(0.f, 0.f, 0.f, 0.f);
            if (node0 + row < n)
                v = *(const float4*)&x[(size_t)(node0 + row) * INC + ch * 64 + col];
            *(float4*)&xs[row * 68 + col] = v;
        }
        // stage W chunk: rows ch*64..+63
        #pragma unroll
        for (int p = 0; p < 4; ++p) {
            int c = t + p * 256;
            *(float4*)&Ws[c * 4] = *(const float4*)&Win[(size_t)(ch * 64) * HID + c * 4];
        }
        __syncthreads();

        #pragma unroll 4
        for (int k4 = 0; k4 < 16; ++k4) {
            float4 xv[8];
            #pragma unroll
            for (int i = 0; i < 8; ++i)
                xv[i] = *(const float4*)&xs[(i * 16 + ry) * 68 + k4 * 4];
            #pragma unroll
            for (int kk = 0; kk < 4; ++kk) {
                float4 w = *(const float4*)&Ws[(k4 * 4 + kk) * HID + cx * 4];
                #pragma unroll
                for (int i = 0; i < 8; ++i) {
                    float xval = reinterpret_cast<const float*>(&xv[i])[kk];
                    acc[i][0] = fmaf(xval, w.x, acc[i][0]);
                    acc[i][1] = fmaf(xval, w.y, acc[i][1]);
                    acc[i][2] = fmaf(xval, w.z, acc[i][2]);
                    acc[i][3] = fmaf(xval, w.w, acc[i][3]);
                }
            }
        }
    }

    const float4 bv  = *(const float4*)&bin[cx * 4];
    const float4 wpv = *(const float4*)&wp[cx * 4];
    const float4 wiv = *(const float4*)&attw[cx * 4];
    const float4 wjv = *(const float4*)&attw[HID + cx * 4];

    #pragma unroll
    for (int i = 0; i < 8; ++i) {
        const int row = i * 16 + ry;
        const int node = node0 + row;
        float h0v = fmaxf(acc[i][0] + bv.x, 0.f);
        float h1v = fmaxf(acc[i][1] + bv.y, 0.f);
        float h2v = fmaxf(acc[i][2] + bv.z, 0.f);
        float h3v = fmaxf(acc[i][3] + bv.w, 0.f);
        if (node < n) {
            float4 hv = make_float4(h0v, h1v, h2v, h3v);
            *(float4*)&h0[(size_t)node * HID + cx * 4] = hv;
        }
        float vd = h0v + h1v + h2v + h3v;
        float vw = h0v * wpv.x + h1v * wpv.y + h2v * wpv.z + h3v * wpv.w;
        float vi = h0v * wiv.x + h1v * wiv.y + h2v * wiv.z + h3v * wiv.w;
        float vj = h0v * wjv.x + h1v * wjv.y + h2v * wjv.z + h3v * wjv.w;
        #pragma unroll
        for (int m = 1; m < 16; m <<= 1) {
            vd += __shfl_xor(vd, m);
            vw += __shfl_xor(vw, m);
            vi += __shfl_xor(vi, m);
            vj += __shfl_xor(vj, m);
        }
        if (cx == 0 && node < n) {
            delta[node] = vd; hwp[node] = vw; ai[node] = vi; aj[node] = vj;
        }
    }
}

// ---------------- Attention prep ----------------
__global__ __launch_bounds__(256) void k_neigh_pi(
    const int* __restrict__ rowptr, const int* __restrict__ csr_src,
    const float* __restrict__ delta, const float* __restrict__ hwp,
    float* __restrict__ pi, int n)
{
    int i = blockIdx.x * 256 + threadIdx.x;
    if (i >= n) return;
    int p0 = rowptr[i], p1 = rowptr[i + 1];
    float s = 0.f;
    for (int p = p0; p < p1; ++p) s += delta[csr_src[p]];
    float v = hwp[i] + s;
    pi[i] = 1.f / (1.f + expf(-v));
}

__global__ __launch_bounds__(256) void k_att(
    const int* __restrict__ rowptr, const int* __restrict__ csr_src,
    const float* __restrict__ ai, const float* __restrict__ aj,
    const float* __restrict__ pi, const float* __restrict__ attw,
    const float* __restrict__ attb,
    float* __restrict__ alpha_csr, int n)
{
    int i = blockIdx.x * 256 + threadIdx.x;
    if (i >= n) return;
    const float wpe = attw[2 * HID];
    const float ab  = attb[0];
    int p0 = rowptr[i], p1 = rowptr[i + 1];
    float aid = ai[i];
    float den = 0.f;
    for (int p = p0; p < p1; ++p) {
        int s = csr_src[p];
        float v = aid + aj[s] + pi[s] * wpe + ab;
        v = v > 0.f ? v : 0.2f * v;
        float ev = expf(v);
        alpha_csr[p] = ev;
        den += ev;
    }
    float inv = 1.f / (den + 1e-16f);
    for (int p = p0; p < p1; ++p) alpha_csr[p] *= inv;
}

// ---------------- Fused layer: gather + GEMM (+ optional output GEMM) ------
// h_next = relu( (Sum_e alpha_e * h[src_e]) @ W + sal * b ),  sal = deg>0 ? 1 : 0
// DO_OUT: additionally out = h_next_tile @ Wout + bout (h_next not stored).
template<int DO_OUT>
__global__ __launch_bounds__(256) void k_layer(
    const int* __restrict__ rowptr, const int* __restrict__ csr_src,
    const float* __restrict__ alpha_csr, const float* __restrict__ hin,
    const float* __restrict__ W, const float* __restrict__ b,
    const float* __restrict__ Wo, const float* __restrict__ bo,
    float* __restrict__ hout, float* __restrict__ out40, int n)
{
    __shared__ float Ts[64 * 68];                 // 17.4 KB gathered tile
    __shared__ float Ws[64 * 64];                 // 16 KB
    __shared__ float Wos[DO_OUT ? 64 * 40 : 4];   // 10 KB if DO_OUT
    __shared__ float sal[64];

    const int t = threadIdx.x;
    const int node0 = blockIdx.x * 64;
    const int wave = t >> 6;
    const int lane = t & 63;
    const int g = lane >> 4;          // edge-group 0..3
    const int q = lane & 15;          // channel quad

    // stage W (and Wout)
    #pragma unroll
    for (int p = 0; p < 4; ++p) {
        int c = t + p * 256;
        *(float4*)&Ws[c * 4] = *(const float4*)&W[c * 4];
    }
    if (DO_OUT) {
        #pragma unroll
        for (int p = 0; p < 3; ++p) {
            int c = t + p * 256;
            if (c < 640) *(float4*)&Wos[c * 4] = *(const float4*)&Wo[c * 4];
        }
    }

    // ---- Phase 1: gather T = Sum alpha * hin[src] (wave per node, 16 nodes) ----
    for (int i = 0; i < 16; ++i) {
        const int r = wave * 16 + i;
        const int node = node0 + r;
        float4 accA = make_float4(0.f, 0.f, 0.f, 0.f);
        float4 accB = make_float4(0.f, 0.f, 0.f, 0.f);
        float salv = 0.f;
        if (node < n) {
            const int p0 = rowptr[node], p1 = rowptr[node + 1];
            salv = (p1 > p0) ? 1.f : 0.f;
            for (int base = p0; base < p1; base += 64) {
                int m = p1 - base; if (m > 64) m = 64;
                float a_l = 0.f; int s_l = 0;
                if (lane < m) { a_l = alpha_csr[base + lane]; s_l = csr_src[base + lane]; }
                int j = 0;
                for (; j + 8 <= m; j += 8) {
                    float a1 = __shfl(a_l, j + g);     int s1 = __shfl(s_l, j + g);
                    float a2 = __shfl(a_l, j + 4 + g); int s2 = __shfl(s_l, j + 4 + g);
                    float4 v1 = *(const float4*)&hin[(size_t)s1 * HID + q * 4];
                    float4 v2 = *(const float4*)&hin[(size_t)s2 * HID + q * 4];
                    accA.x = fmaf(a1, v1.x, accA.x); accA.y = fmaf(a1, v1.y, accA.y);
                    accA.z = fmaf(a1, v1.z, accA.z); accA.w = fmaf(a1, v1.w, accA.w);
                    accB.x = fmaf(a2, v2.x, accB.x); accB.y = fmaf(a2, v2.y, accB.y);
                    accB.z = fmaf(a2, v2.z, accB.z); accB.w = fmaf(a2, v2.w, accB.w);
                }
                for (; j < m; j += 4) {
                    int e = j + g;
                    if (e < m) {
                        float a = __shfl(a_l, e); int s = __shfl(s_l, e);
                        float4 v = *(const float4*)&hin[(size_t)s * HID + q * 4];
                        accA.x = fmaf(a, v.x, accA.x); accA.y = fmaf(a, v.y, accA.y);
                        accA.z = fmaf(a, v.z, accA.z); accA.w = fmaf(a, v.w, accA.w);
                    }
                }
            }
        }
        float4 acc = make_float4(accA.x + accB.x, accA.y + accB.y,
                                 accA.z + accB.z, accA.w + accB.w);
        #pragma unroll
        for (int m2 = 16; m2 <= 32; m2 <<= 1) {
            acc.x += __shfl_xor(acc.x, m2);
            acc.y += __shfl_xor(acc.y, m2);
            acc.z += __shfl_xor(acc.z, m2);
            acc.w += __shfl_xor(acc.w, m2);
        }
        if (g == 0) {
            *(float4*)&Ts[r * 68 + q * 4] = acc;
            if (lane == 0) sal[r] = salv;
        }
    }
    __syncthreads();

    // ---- Phase 2: h_next(tile) = relu(T @ W + sal*b) ----
    const int cx = t & 15;
    const int ny = t >> 4;
    float acc2[4][4];
    #pragma unroll
    for (int i = 0; i < 4; ++i)
        #pragma unroll
        for (int j = 0; j < 4; ++j) acc2[i][j] = 0.f;

    #pragma unroll 4
    for (int k4 = 0; k4 < 16; ++k4) {
        float4 xv[4];
        #pragma unroll
        for (int i = 0; i < 4; ++i)
            xv[i] = *(const float4*)&Ts[(i * 16 + ny) * 68 + k4 * 4];
        #pragma unroll
        for (int kk = 0; kk < 4; ++kk) {
            float4 w = *(const float4*)&Ws[(k4 * 4 + kk) * HID + cx * 4];
            #pragma unroll
            for (int i = 0; i < 4; ++i) {
                float xval = reinterpret_cast<const float*>(&xv[i])[kk];
                acc2[i][0] = fmaf(xval, w.x, acc2[i][0]);
                acc2[i][1] = fmaf(xval, w.y, acc2[i][1]);
                acc2[i][2] = fmaf(xval, w.z, acc2[i][2]);
                acc2[i][3] = fmaf(xval, w.w, acc2[i][3]);
            }
        }
    }

    const float4 bv = *(const float4*)&b[cx * 4];
    float hreg[4][4];
    #pragma unroll
    for (int i = 0; i < 4; ++i) {
        const int row = i * 16 + ny;
        const float s = sal[row];
        hreg[i][0] = fmaxf(acc2[i][0] + s * bv.x, 0.f);
        hreg[i][1] = fmaxf(acc2[i][1] + s * bv.y, 0.f);
        hreg[i][2] = fmaxf(acc2[i][2] + s * bv.z, 0.f);
        hreg[i][3] = fmaxf(acc2[i][3] + s * bv.w, 0.f);
        if (!DO_OUT) {
            const int node = node0 + row;
            if (node < n) {
                float4 hv = make_float4(hreg[i][0], hreg[i][1], hreg[i][2], hreg[i][3]);
                *(float4*)&hout[(size_t)node * HID + cx * 4] = hv;
            }
        }
    }

    if (DO_OUT) {
        // ---- Phase 3: write h3 tile back into Ts, then out = T @ Wout + bout ----
        __syncthreads();   // all phase-2 reads of Ts done
        #pragma unroll
        for (int i = 0; i < 4; ++i)
            *(float4*)&Ts[(i * 16 + ny) * 68 + cx * 4] =
                make_float4(hreg[i][0], hreg[i][1], hreg[i][2], hreg[i][3]);
        __syncthreads();

        const int cx2 = t & 7;        // 5 cols: 5*cx2..+4
        const int ny2 = t >> 3;       // rows i2*32 + ny2
        float acc3[2][5];
        #pragma unroll
        for (int j = 0; j < 5; ++j) {
            #pragma unroll
            for (int i = 0; i < 2; ++i) acc3[i][j] = 0.f;
        }
        #pragma unroll 4
        for (int k4 = 0; k4 < 16; ++k4) {
            float4 xv2[2];
            #pragma unroll
            for (int i = 0; i < 2; ++i)
                xv2[i] = *(const float4*)&Ts[(i * 32 + ny2) * 68 + k4 * 4];
            #pragma unroll
            for (int kk = 0; kk < 4; ++kk) {
                const int k = k4 * 4 + kk;
                float w[5];
                #pragma unroll
                for (int j = 0; j < 5; ++j) w[j] = Wos[k * 40 + 5 * cx2 + j];
                #pragma unroll
                for (int i = 0; i < 2; ++i) {
                    float xval = reinterpret_cast<const float*>(&xv2[i])[kk];
                    #pragma unroll
                    for (int j = 0; j < 5; ++j)
                        acc3[i][j] = fmaf(xval, w[j], acc3[i][j]);
                }
            }
        }
        #pragma unroll
        for (int i = 0; i < 2; ++i) {
            const int node = node0 + i * 32 + ny2;
            if (node < n) {
                #pragma unroll
                for (int j = 0; j < 5; ++j)
                    out40[(size_t)node * 40 + 5 * cx2 + j] = acc3[i][j] + bo[5 * cx2 + j];
            }
        }
    }
}

extern "C" void kernel_launch(void* const* d_in, const int* in_sizes, int n_in,
                              void* d_out, int out_size, void* d_ws, size_t ws_size,
                              hipStream_t stream) {
    const float* x    = (const float*)d_in[0];
    const int*   ei   = (const int*)d_in[1];
    const float* Win  = (const float*)d_in[2];
    const float* bin  = (const float*)d_in[3];
    const float* wp   = (const float*)d_in[4];
    const float* attw = (const float*)d_in[5];
    const float* attb = (const float*)d_in[6];
    const float* Wout = (const float*)d_in[7];
    const float* bout = (const float*)d_in[8];
    const float* W0   = (const float*)d_in[9];
    const float* b0   = (const float*)d_in[10];
    const float* W1   = (const float*)d_in[11];
    const float* b1   = (const float*)d_in[12];
    const float* W2   = (const float*)d_in[13];
    const float* b2   = (const float*)d_in[14];

    const int N = in_sizes[0] / INC;
    const int E = in_sizes[1] / 2;
    const int* src = ei;
    const int* dst = ei + E;
    float* out = (float*)d_out;

    char* ws = (char*)d_ws;
    size_t off = 0;
    auto alloc = [&](size_t bytes) -> void* {
        void* p = ws + off;
        off = (off + bytes + 255) & ~(size_t)255;
        return p;
    };
    float* A       = (float*)alloc((size_t)N * HID * 4);   // h0
    float* Bf      = (float*)alloc((size_t)N * HID * 4);   // h1
    float* C       = (float*)alloc((size_t)N * HID * 4);   // h2
    float* delta   = (float*)alloc((size_t)N * 4);
    float* hwp     = (float*)alloc((size_t)N * 4);
    float* ai      = (float*)alloc((size_t)N * 4);
    float* aj      = (float*)alloc((size_t)N * 4);
    float* pi      = (float*)alloc((size_t)N * 4);
    int*   deg     = (int*)alloc((size_t)N * 4);
    int*   rowptr  = (int*)alloc((size_t)(N + 1) * 4);
    int*   cursor  = (int*)alloc((size_t)N * 4);
    int*   bsum    = (int*)alloc(256 * 4);
    int*   csr_src = (int*)alloc((size_t)E * 4);
    float* alpha   = (float*)alloc((size_t)E * 4);

    const int tileBlocks64  = (N + 63) / 64;
    const int tileBlocks128 = (N + 127) / 128;
    const int edgeBlocks    = (E + 255) / 256;
    const int nodeBlocks256 = (N + 255) / 256;
    const int scanBlocks    = (N + 1023) / 1024;

    // ---- CSR build ----
    hipMemsetAsync(deg, 0, (size_t)N * 4, stream);
    k_degree<<<edgeBlocks, 256, 0, stream>>>(dst, deg, E);
    k_scan1<<<scanBlocks, 256, 0, stream>>>(deg, rowptr, bsum, N);
    k_scan2<<<1, 128, 0, stream>>>(bsum, scanBlocks);
    k_scan3<<<scanBlocks, 256, 0, stream>>>(rowptr, cursor, bsum, N, E);
    k_place<<<edgeBlocks, 256, 0, stream>>>(src, dst, cursor, csr_src, E);

    // ---- node features + attention ----
    k_in_gemm<<<tileBlocks128, 256, 0, stream>>>(x, Win, bin, wp, attw,
                                                 A, delta, hwp, ai, aj, N);
    k_neigh_pi<<<nodeBlocks256, 256, 0, stream>>>(rowptr, csr_src, delta, hwp, pi, N);
    k_att<<<nodeBlocks256, 256, 0, stream>>>(rowptr, csr_src, ai, aj, pi,
                                             attw, attb, alpha, N);

    // ---- fused layers ----
    k_layer<0><<<tileBlocks64, 256, 0, stream>>>(rowptr, csr_src, alpha, A,
                                                 W0, b0, Wout, bout, Bf, out, N);
    k_layer<0><<<tileBlocks64, 256, 0, stream>>>(rowptr, csr_src, alpha, Bf,
                                                 W1, b1, Wout, bout, C, out, N);
    k_layer<1><<<tileBlocks64, 256, 0, stream>>>(rowptr, csr_src, alpha, C,
                                                 W2, b2, Wout, bout, A, out, N);
}

// Round 7
// 352.375 us; speedup vs baseline: 1.2473x; 1.2473x over previous
//
#include <hip/hip_runtime.h>
#include <math.h>

// ---------------------------------------------------------------------------
// AGNNet: GAT-like 3-layer GNN. N=100000 nodes, E=800000 edges, HID=64.
// R7: recover R4 numerics (passed, absmax 9.8e-4) + order-safe changes only:
//  - in_gemm K-chunked (bias-init, k ascending -> bit-identical to R4),
//    LDS 33.4 KB -> 4 blocks/CU
//  - megakernel in_gemm || degree-count (int atomics commute: no numeric risk)
//  - CSR rows sorted by edge id (deterministic, matches reference
//    segment_sum order) via eid payload + per-row insertion sort
//  - gather/gemm64/out_gemm/neigh/att: bit-exact R4 versions
// ---------------------------------------------------------------------------

#define HID 64
#define INC 128

// ---------------- Megakernel: in_gemm (bid%3==0) || degree count ----------
__global__ __launch_bounds__(256) void k_ingemm_deg(
    const float* __restrict__ x, const float* __restrict__ Win,
    const float* __restrict__ bin, const float* __restrict__ wp,
    const float* __restrict__ attw,
    float* __restrict__ h0, float* __restrict__ delta, float* __restrict__ hwp,
    float* __restrict__ ai, float* __restrict__ aj, int n,
    const int* __restrict__ dst, int* __restrict__ deg, int E)
{
    __shared__ float xs[64 * 68];     // 17.4 KB
    __shared__ float Ws[64 * 64];     // 16 KB (one K-chunk)
    const int t = threadIdx.x;
    const int bid = blockIdx.x;

    if (bid % 3 != 0) {
        // ---- degree branch: atomic int counts (order-independent) ----
        const int cid = (bid / 3) * 2 + (bid % 3 - 1);
        const int e = cid * 256 + t;
        if (e < E) atomicAdd(deg + dst[e], 1);
        return;
    }

    // ---- in_gemm branch: 64-node tile, K in 2x64 ascending chunks ----
    const int node0 = (bid / 3) * 64;
    const int cx = t & 15;
    const int ny = t >> 4;

    // bias-init (same as R4) so FMA sequence is bit-identical to R4
    float acc[4][4];
    const float4 bv = *(const float4*)&bin[cx * 4];
    #pragma unroll
    for (int i = 0; i < 4; ++i) {
        acc[i][0] = bv.x; acc[i][1] = bv.y; acc[i][2] = bv.z; acc[i][3] = bv.w;
    }

    #pragma unroll
    for (int ch = 0; ch < 2; ++ch) {
        if (ch) __syncthreads();      // all reads of previous chunk done
        // stage x chunk: 64 rows x 64 cols
        #pragma unroll
        for (int p = 0; p < 4; ++p) {
            int c = t + p * 256;
            int row = c >> 4;
            int col = (c & 15) * 4;
            float4 v = make_float4(0.f, 0.f, 0.f, 0.f);
            if (node0 + row < n)
                v = *(const float4*)&x[(size_t)(node0 + row) * INC + ch * 64 + col];
            *(float4*)&xs[row * 68 + col] = v;
        }
        // stage W chunk rows ch*64..+63 (4096 consecutive floats)
        #pragma unroll
        for (int p = 0; p < 4; ++p) {
            int c = t + p * 256;
            *(float4*)&Ws[c * 4] = *(const float4*)&Win[(size_t)ch * 64 * HID + c * 4];
        }
        __syncthreads();

        #pragma unroll 4
        for (int k4 = 0; k4 < 16; ++k4) {
            float4 xv[4];
            #pragma unroll
            for (int i = 0; i < 4; ++i)
                xv[i] = *(const float4*)&xs[(i * 16 + ny) * 68 + k4 * 4];
            #pragma unroll
            for (int kk = 0; kk < 4; ++kk) {
                float4 w = *(const float4*)&Ws[(k4 * 4 + kk) * HID + cx * 4];
                #pragma unroll
                for (int i = 0; i < 4; ++i) {
                    float xval = reinterpret_cast<const float*>(&xv[i])[kk];
                    acc[i][0] = fmaf(xval, w.x, acc[i][0]);
                    acc[i][1] = fmaf(xval, w.y, acc[i][1]);
                    acc[i][2] = fmaf(xval, w.z, acc[i][2]);
                    acc[i][3] = fmaf(xval, w.w, acc[i][3]);
                }
            }
        }
    }

    const float4 wpv = *(const float4*)&wp[cx * 4];
    const float4 wiv = *(const float4*)&attw[cx * 4];
    const float4 wjv = *(const float4*)&attw[HID + cx * 4];

    #pragma unroll
    for (int i = 0; i < 4; ++i) {
        const int node = node0 + i * 16 + ny;
        float h0v = fmaxf(acc[i][0], 0.f);
        float h1v = fmaxf(acc[i][1], 0.f);
        float h2v = fmaxf(acc[i][2], 0.f);
        float h3v = fmaxf(acc[i][3], 0.f);
        if (node < n) {
            float4 hv = make_float4(h0v, h1v, h2v, h3v);
            *(float4*)&h0[(size_t)node * HID + cx * 4] = hv;
        }
        float vd = h0v + h1v + h2v + h3v;
        float vw = h0v * wpv.x + h1v * wpv.y + h2v * wpv.z + h3v * wpv.w;
        float vi = h0v * wiv.x + h1v * wiv.y + h2v * wiv.z + h3v * wiv.w;
        float vj = h0v * wjv.x + h1v * wjv.y + h2v * wjv.z + h3v * wjv.w;
        #pragma unroll
        for (int m = 1; m < 16; m <<= 1) {
            vd += __shfl_xor(vd, m);
            vw += __shfl_xor(vw, m);
            vi += __shfl_xor(vi, m);
            vj += __shfl_xor(vj, m);
        }
        if (cx == 0 && node < n) {
            delta[node] = vd; hwp[node] = vw; ai[node] = vi; aj[node] = vj;
        }
    }
}

// ---------------- CSR build ----------------
__global__ __launch_bounds__(256) void k_scan1(
    const int* __restrict__ deg, int* __restrict__ rowptr,
    int* __restrict__ bsum, int n)
{
    __shared__ int sdata[256];
    const int t = threadIdx.x;
    const int i0 = blockIdx.x * 1024 + t * 4;
    int v[4];
    #pragma unroll
    for (int j = 0; j < 4; ++j) v[j] = (i0 + j < n) ? deg[i0 + j] : 0;
    int ts = v[0] + v[1] + v[2] + v[3];
    sdata[t] = ts;
    __syncthreads();
    for (int off = 1; off < 256; off <<= 1) {
        int add = (t >= off) ? sdata[t - off] : 0;
        __syncthreads();
        sdata[t] += add;
        __syncthreads();
    }
    int excl = sdata[t] - ts;
    int run = excl;
    #pragma unroll
    for (int j = 0; j < 4; ++j) {
        if (i0 + j < n) rowptr[i0 + j] = run;
        run += v[j];
    }
    if (t == 255) bsum[blockIdx.x] = sdata[255];
}

__global__ __launch_bounds__(128) void k_scan2(int* __restrict__ bsum, int B)
{
    __shared__ int sdata[128];
    const int t = threadIdx.x;
    int v = (t < B) ? bsum[t] : 0;
    sdata[t] = v;
    __syncthreads();
    for (int off = 1; off < 128; off <<= 1) {
        int add = (t >= off) ? sdata[t - off] : 0;
        __syncthreads();
        sdata[t] += add;
        __syncthreads();
    }
    if (t < B) bsum[t] = sdata[t] - v;
}

__global__ __launch_bounds__(256) void k_scan3(
    int* __restrict__ rowptr, int* __restrict__ cursor,
    const int* __restrict__ bsum, int n, int E)
{
    const int t = threadIdx.x;
    const int i0 = blockIdx.x * 1024 + t * 4;
    const int add = bsum[blockIdx.x];
    #pragma unroll
    for (int j = 0; j < 4; ++j) {
        int i = i0 + j;
        if (i < n) {
            int r = rowptr[i] + add;
            rowptr[i] = r;
            cursor[i] = r;
        }
    }
    if (blockIdx.x == 0 && t == 0) rowptr[n] = E;
}

// place edge IDs (payload), arbitrary order; sorted next.
__global__ __launch_bounds__(256) void k_place(
    const int* __restrict__ dst, int* __restrict__ cursor,
    int* __restrict__ csr_eid, int E)
{
    int e = blockIdx.x * 256 + threadIdx.x;
    if (e < E) {
        int slot = atomicAdd(cursor + dst[e], 1);
        csr_eid[slot] = e;
    }
}

// sort each row by edge id (ascending -> reference segment order, and
// deterministic); materialize csr_src = src[eid].
__global__ __launch_bounds__(256) void k_sortrow(
    const int* __restrict__ rowptr, int* __restrict__ csr_eid,
    const int* __restrict__ src, int* __restrict__ csr_src, int n)
{
    int i = blockIdx.x * 256 + threadIdx.x;
    if (i >= n) return;
    const int p0 = rowptr[i], p1 = rowptr[i + 1];
    for (int a = p0 + 1; a < p1; ++a) {
        int key = csr_eid[a];
        int b = a - 1;
        while (b >= p0 && csr_eid[b] > key) {
            csr_eid[b + 1] = csr_eid[b];
            --b;
        }
        csr_eid[b + 1] = key;
    }
    for (int p = p0; p < p1; ++p) csr_src[p] = src[csr_eid[p]];
}

// ---------------- Attention prep ----------------
__global__ __launch_bounds__(256) void k_neigh_pi(
    const int* __restrict__ rowptr, const int* __restrict__ csr_src,
    const float* __restrict__ delta, const float* __restrict__ hwp,
    float* __restrict__ pi, int n)
{
    int i = blockIdx.x * 256 + threadIdx.x;
    if (i >= n) return;
    int p0 = rowptr[i], p1 = rowptr[i + 1];
    float s = 0.f;
    for (int p = p0; p < p1; ++p) s += delta[csr_src[p]];
    float v = hwp[i] + s;
    pi[i] = 1.f / (1.f + expf(-v));
}

__global__ __launch_bounds__(256) void k_att(
    const int* __restrict__ rowptr, const int* __restrict__ csr_src,
    const float* __restrict__ ai, const float* __restrict__ aj,
    const float* __restrict__ pi, const float* __restrict__ attw,
    const float* __restrict__ attb,
    float* __restrict__ alpha_csr, int n)
{
    int i = blockIdx.x * 256 + threadIdx.x;
    if (i >= n) return;
    const float wpe = attw[2 * HID];
    const float ab  = attb[0];
    int p0 = rowptr[i], p1 = rowptr[i + 1];
    float aid = ai[i];
    float den = 0.f;
    for (int p = p0; p < p1; ++p) {
        int s = csr_src[p];
        float v = aid + aj[s] + pi[s] * wpe + ab;
        v = v > 0.f ? v : 0.2f * v;
        float ev = expf(v);
        alpha_csr[p] = ev;
        den += ev;
    }
    float inv = 1.f / (den + 1e-16f);
    for (int p = p0; p < p1; ++p) alpha_csr[p] *= inv;
}

// ---------------- GEMM 64x64 (R4 exact) ----------------
__global__ __launch_bounds__(256) void k_gemm64(
    const float* __restrict__ hin, const float* __restrict__ W,
    const float* __restrict__ b, float* __restrict__ hout, int n, int relu_in)
{
    __shared__ float xs[64 * 68];
    __shared__ float Ws[HID * HID];
    const int t = threadIdx.x;
    const int node0 = blockIdx.x * 64;

    #pragma unroll
    for (int p = 0; p < 4; ++p) {
        int c = t + p * 256;
        *(float4*)&Ws[c * 4] = *(const float4*)&W[c * 4];
    }
    #pragma unroll
    for (int p = 0; p < 4; ++p) {
        int c = t + p * 256;
        int row = c >> 4;
        int col = (c & 15) * 4;
        float4 v = make_float4(0.f, 0.f, 0.f, 0.f);
        if (node0 + row < n) v = *(const float4*)&hin[(size_t)(node0 + row) * HID + col];
        if (relu_in) {
            v.x = fmaxf(v.x, 0.f); v.y = fmaxf(v.y, 0.f);
            v.z = fmaxf(v.z, 0.f); v.w = fmaxf(v.w, 0.f);
        }
        *(float4*)&xs[row * 68 + col] = v;
    }
    __syncthreads();

    const int cx = t & 15;
    const int ny = t >> 4;
    float acc[4][4];
    const float4 bv = *(const float4*)&b[cx * 4];
    #pragma unroll
    for (int i = 0; i < 4; ++i) {
        acc[i][0] = bv.x; acc[i][1] = bv.y; acc[i][2] = bv.z; acc[i][3] = bv.w;
    }

    #pragma unroll 4
    for (int k4 = 0; k4 < 16; ++k4) {
        float4 xv[4];
        #pragma unroll
        for (int i = 0; i < 4; ++i)
            xv[i] = *(const float4*)&xs[(i * 16 + ny) * 68 + k4 * 4];
        #pragma unroll
        for (int kk = 0; kk < 4; ++kk) {
            float4 w = *(const float4*)&Ws[(k4 * 4 + kk) * HID + cx * 4];
            #pragma unroll
            for (int i = 0; i < 4; ++i) {
                float xval = reinterpret_cast<const float*>(&xv[i])[kk];
                acc[i][0] = fmaf(xval, w.x, acc[i][0]);
                acc[i][1] = fmaf(xval, w.y, acc[i][1]);
                acc[i][2] = fmaf(xval, w.z, acc[i][2]);
                acc[i][3] = fmaf(xval, w.w, acc[i][3]);
            }
        }
    }

    #pragma unroll
    for (int i = 0; i < 4; ++i) {
        const int node = node0 + i * 16 + ny;
        if (node < n) {
            float4 hv = make_float4(acc[i][0], acc[i][1], acc[i][2], acc[i][3]);
            *(float4*)&hout[(size_t)node * HID + cx * 4] = hv;
        }
    }
}

// ---------------- Gather (R4 exact): out[d] = Sum alpha * hl[src] ---------
__global__ __launch_bounds__(256) void k_gather(
    const int* __restrict__ rowptr, const int* __restrict__ csr_src,
    const float* __restrict__ alpha_csr, const float* __restrict__ hl,
    float* __restrict__ out, int n)
{
    const int wave = threadIdx.x >> 6;
    const int lane = threadIdx.x & 63;
    const int g    = lane >> 4;
    const int q    = lane & 15;
    const int node = blockIdx.x * 4 + wave;
    if (node >= n) return;

    const int p0 = rowptr[node], p1 = rowptr[node + 1];
    float4 acc = make_float4(0.f, 0.f, 0.f, 0.f);

    for (int base = p0; base < p1; base += 64) {
        int m = p1 - base; if (m > 64) m = 64;
        float a_l = 0.f; int s_l = 0;
        if (lane < m) { a_l = alpha_csr[base + lane]; s_l = csr_src[base + lane]; }
        for (int j = 0; j < m; j += 4) {
            const int e = j + g;
            float a = __shfl(a_l, e);
            int   s = __shfl(s_l, e);
            if (e < m) {
                float4 v = *(const float4*)&hl[(size_t)s * HID + q * 4];
                acc.x = fmaf(a, v.x, acc.x);
                acc.y = fmaf(a, v.y, acc.y);
                acc.z = fmaf(a, v.z, acc.z);
                acc.w = fmaf(a, v.w, acc.w);
            }
        }
    }
    #pragma unroll
    for (int m2 = 16; m2 <= 32; m2 <<= 1) {
        acc.x += __shfl_xor(acc.x, m2);
        acc.y += __shfl_xor(acc.y, m2);
        acc.z += __shfl_xor(acc.z, m2);
        acc.w += __shfl_xor(acc.w, m2);
    }
    if (g == 0)
        *(float4*)&out[(size_t)node * HID + q * 4] = acc;
}

// ---------------- Output GEMM 64x40 (R4 exact) ----------------
__global__ __launch_bounds__(256) void k_out_gemm(
    const float* __restrict__ hin, const float* __restrict__ W,
    const float* __restrict__ b, float* __restrict__ out, int n)
{
    __shared__ float xs[128 * 68];
    __shared__ float Ws[HID * 40];
    const int t = threadIdx.x;
    const int node0 = blockIdx.x * 128;

    #pragma unroll
    for (int p = 0; p < 3; ++p) {
        int c = t + p * 256;
        if (c < 640) *(float4*)&Ws[c * 4] = *(const float4*)&W[c * 4];
    }
    #pragma unroll
    for (int p = 0; p < 8; ++p) {
        int c = t + p * 256;
        int row = c >> 4;
        int col = (c & 15) * 4;
        float4 v = make_float4(0.f, 0.f, 0.f, 0.f);
        if (node0 + row < n) v = *(const float4*)&hin[(size_t)(node0 + row) * HID + col];
        v.x = fmaxf(v.x, 0.f); v.y = fmaxf(v.y, 0.f);
        v.z = fmaxf(v.z, 0.f); v.w = fmaxf(v.w, 0.f);
        *(float4*)&xs[row * 68 + col] = v;
    }
    __syncthreads();

    const int cx = t & 7;
    const int ny = t >> 3;
    float acc[4][5];
    #pragma unroll
    for (int j = 0; j < 5; ++j) {
        float bj = b[5 * cx + j];
        #pragma unroll
        for (int i = 0; i < 4; ++i) acc[i][j] = bj;
    }

    #pragma unroll 4
    for (int k4 = 0; k4 < 16; ++k4) {
        float4 xv[4];
        #pragma unroll
        for (int i = 0; i < 4; ++i)
            xv[i] = *(const float4*)&xs[(i * 32 + ny) * 68 + k4 * 4];
        #pragma unroll
        for (int kk = 0; kk < 4; ++kk) {
            int k = k4 * 4 + kk;
            float w[5];
            #pragma unroll
            for (int j = 0; j < 5; ++j) w[j] = Ws[k * 40 + 5 * cx + j];
            #pragma unroll
            for (int i = 0; i < 4; ++i) {
                float xval = reinterpret_cast<const float*>(&xv[i])[kk];
                #pragma unroll
                for (int j = 0; j < 5; ++j)
                    acc[i][j] = fmaf(xval, w[j], acc[i][j]);
            }
        }
    }

    #pragma unroll
    for (int i = 0; i < 4; ++i) {
        const int node = node0 + i * 32 + ny;
        if (node < n) {
            #pragma unroll
            for (int j = 0; j < 5; ++j)
                out[(size_t)node * 40 + 5 * cx + j] = acc[i][j];
        }
    }
}

extern "C" void kernel_launch(void* const* d_in, const int* in_sizes, int n_in,
                              void* d_out, int out_size, void* d_ws, size_t ws_size,
                              hipStream_t stream) {
    const float* x    = (const float*)d_in[0];
    const int*   ei   = (const int*)d_in[1];
    const float* Win  = (const float*)d_in[2];
    const float* bin  = (const float*)d_in[3];
    const float* wp   = (const float*)d_in[4];
    const float* attw = (const float*)d_in[5];
    const float* attb = (const float*)d_in[6];
    const float* Wout = (const float*)d_in[7];
    const float* bout = (const float*)d_in[8];
    const float* W0   = (const float*)d_in[9];
    const float* b0   = (const float*)d_in[10];
    const float* W1   = (const float*)d_in[11];
    const float* b1   = (const float*)d_in[12];
    const float* W2   = (const float*)d_in[13];
    const float* b2   = (const float*)d_in[14];

    const int N = in_sizes[0] / INC;
    const int E = in_sizes[1] / 2;
    const int* src = ei;
    const int* dst = ei + E;
    float* out = (float*)d_out;

    char* ws = (char*)d_ws;
    size_t off = 0;
    auto alloc = [&](size_t bytes) -> void* {
        void* p = ws + off;
        off = (off + bytes + 255) & ~(size_t)255;
        return p;
    };
    float* A       = (float*)alloc((size_t)N * HID * 4);
    float* Bf      = (float*)alloc((size_t)N * HID * 4);
    float* C       = (float*)alloc((size_t)N * HID * 4);
    float* delta   = (float*)alloc((size_t)N * 4);
    float* hwp     = (float*)alloc((size_t)N * 4);
    float* ai      = (float*)alloc((size_t)N * 4);
    float* aj      = (float*)alloc((size_t)N * 4);
    float* pi      = (float*)alloc((size_t)N * 4);
    int*   deg     = (int*)alloc((size_t)N * 4);
    int*   rowptr  = (int*)alloc((size_t)(N + 1) * 4);
    int*   cursor  = (int*)alloc((size_t)N * 4);
    int*   bsum    = (int*)alloc(256 * 4);
    int*   csr_eid = (int*)alloc((size_t)E * 4);
    int*   csr_src = (int*)alloc((size_t)E * 4);
    float* alpha   = (float*)alloc((size_t)E * 4);

    const int tileBlocks64  = (N + 63) / 64;          // 1563
    const int tileBlocks128 = (N + 127) / 128;
    const int edgeBlocks    = (E + 255) / 256;        // 3125
    const int nodeBlocks256 = (N + 255) / 256;
    const int nodeBlocksW   = (N + 3) / 4;
    const int scanBlocks    = (N + 1023) / 1024;

    // megakernel grid: 1 gemm block : 2 degree blocks; degree ids cover
    // 2*tileBlocks64 = 3126 >= edgeBlocks (guarded by e < E)
    const int fusedBlocks = 3 * tileBlocks64;

    hipMemsetAsync(deg, 0, (size_t)N * 4, stream);

    // ---- in_gemm || degree count ----
    k_ingemm_deg<<<fusedBlocks, 256, 0, stream>>>(
        x, Win, bin, wp, attw, A, delta, hwp, ai, aj, N, dst, deg, E);

    // ---- CSR build (deterministic sorted rows) ----
    k_scan1<<<scanBlocks, 256, 0, stream>>>(deg, rowptr, bsum, N);
    k_scan2<<<1, 128, 0, stream>>>(bsum, scanBlocks);
    k_scan3<<<scanBlocks, 256, 0, stream>>>(rowptr, cursor, bsum, N, E);
    k_place<<<edgeBlocks, 256, 0, stream>>>(dst, cursor, csr_eid, E);
    k_sortrow<<<nodeBlocks256, 256, 0, stream>>>(rowptr, csr_eid, src, csr_src, N);

    // ---- attention ----
    k_neigh_pi<<<nodeBlocks256, 256, 0, stream>>>(rowptr, csr_src, delta, hwp, pi, N);
    k_att<<<nodeBlocks256, 256, 0, stream>>>(rowptr, csr_src, ai, aj, pi,
                                             attw, attb, alpha, N);

    // ---- layers (R4 exact) ----
    k_gemm64<<<tileBlocks64, 256, 0, stream>>>(A, W0, b0, Bf, N, 0);
    k_gather<<<nodeBlocksW, 256, 0, stream>>>(rowptr, csr_src, alpha, Bf, C, N);

    k_gemm64<<<tileBlocks64, 256, 0, stream>>>(C, W1, b1, A, N, 1);
    k_gather<<<nodeBlocksW, 256, 0, stream>>>(rowptr, csr_src, alpha, A, Bf, N);

    k_gemm64<<<tileBlocks64, 256, 0, stream>>>(Bf, W2, b2, C, N, 1);
    k_gather<<<nodeBlocksW, 256, 0, stream>>>(rowptr, csr_src, alpha, C, A, N);

    k_out_gemm<<<tileBlocks128, 256, 0, stream>>>(A, Wout, bout, out, N);
}

// Round 8
// 346.728 us; speedup vs baseline: 1.2676x; 1.0163x over previous
//
#include <hip/hip_runtime.h>
#include <math.h>

// ---------------------------------------------------------------------------
// AGNNet: GAT-like 3-layer GNN. N=100000 nodes, E=800000 edges, HID=64.
// R8 = R7 + XCD-partitioned scatter for degree-count and CSR-place:
// part = blockIdx.x & 7 (round-robin XCD map); each partition owns node range
// [part*psize, (part+1)*psize) -> deg/cursor/csr_eid lines touched by ONE XCD
// (kills the 17x inter-XCD write amplification seen in R7 counters).
// CSR content after sortrow is bit-identical to R7 -> same absmax (9.77e-4).
// ---------------------------------------------------------------------------

#define HID 64
#define INC 128
#define DCHUNK 2048   // edges scanned per degree/place block (8 x 256)

// ---------------- Megakernel: in_gemm (bid<NG) || partitioned degree -------
__global__ __launch_bounds__(256) void k_ingemm_deg(
    const float* __restrict__ x, const float* __restrict__ Win,
    const float* __restrict__ bin, const float* __restrict__ wp,
    const float* __restrict__ attw,
    float* __restrict__ h0, float* __restrict__ delta, float* __restrict__ hwp,
    float* __restrict__ ai, float* __restrict__ aj, int n,
    const int* __restrict__ dst, int* __restrict__ deg, int E,
    int NG, int psize)
{
    __shared__ float xs[64 * 68];     // 17.4 KB
    __shared__ float Ws[64 * 64];     // 16 KB (one K-chunk)
    const int t = threadIdx.x;
    const int bid = blockIdx.x;

    if (bid >= NG) {
        // ---- partitioned degree branch ----
        const int did  = bid - NG;
        const int part = bid & 7;               // = this block's XCD slot
        const int lo   = part * psize;
        const int hi   = lo + psize;
        int e = (did >> 3) * DCHUNK + t;
        #pragma unroll
        for (int it = 0; it < DCHUNK / 256; ++it, e += 256) {
            if (e < E) {
                int d = dst[e];
                if (d >= lo && d < hi) atomicAdd(deg + d, 1);
            }
        }
        return;
    }

    // ---- in_gemm branch: 64-node tile, K in 2x64 ascending chunks ----
    const int node0 = bid * 64;
    const int cx = t & 15;
    const int ny = t >> 4;

    float acc[4][4];
    const float4 bv = *(const float4*)&bin[cx * 4];
    #pragma unroll
    for (int i = 0; i < 4; ++i) {
        acc[i][0] = bv.x; acc[i][1] = bv.y; acc[i][2] = bv.z; acc[i][3] = bv.w;
    }

    #pragma unroll
    for (int ch = 0; ch < 2; ++ch) {
        if (ch) __syncthreads();
        #pragma unroll
        for (int p = 0; p < 4; ++p) {
            int c = t + p * 256;
            int row = c >> 4;
            int col = (c & 15) * 4;
            float4 v = make_float4(0.f, 0.f, 0.f, 0.f);
            if (node0 + row < n)
                v = *(const float4*)&x[(size_t)(node0 + row) * INC + ch * 64 + col];
            *(float4*)&xs[row * 68 + col] = v;
        }
        #pragma unroll
        for (int p = 0; p < 4; ++p) {
            int c = t + p * 256;
            *(float4*)&Ws[c * 4] = *(const float4*)&Win[(size_t)ch * 64 * HID + c * 4];
        }
        __syncthreads();

        #pragma unroll 4
        for (int k4 = 0; k4 < 16; ++k4) {
            float4 xv[4];
            #pragma unroll
            for (int i = 0; i < 4; ++i)
                xv[i] = *(const float4*)&xs[(i * 16 + ny) * 68 + k4 * 4];
            #pragma unroll
            for (int kk = 0; kk < 4; ++kk) {
                float4 w = *(const float4*)&Ws[(k4 * 4 + kk) * HID + cx * 4];
                #pragma unroll
                for (int i = 0; i < 4; ++i) {
                    float xval = reinterpret_cast<const float*>(&xv[i])[kk];
                    acc[i][0] = fmaf(xval, w.x, acc[i][0]);
                    acc[i][1] = fmaf(xval, w.y, acc[i][1]);
                    acc[i][2] = fmaf(xval, w.z, acc[i][2]);
                    acc[i][3] = fmaf(xval, w.w, acc[i][3]);
                }
            }
        }
    }

    const float4 wpv = *(const float4*)&wp[cx * 4];
    const float4 wiv = *(const float4*)&attw[cx * 4];
    const float4 wjv = *(const float4*)&attw[HID + cx * 4];

    #pragma unroll
    for (int i = 0; i < 4; ++i) {
        const int node = node0 + i * 16 + ny;
        float h0v = fmaxf(acc[i][0], 0.f);
        float h1v = fmaxf(acc[i][1], 0.f);
        float h2v = fmaxf(acc[i][2], 0.f);
        float h3v = fmaxf(acc[i][3], 0.f);
        if (node < n) {
            float4 hv = make_float4(h0v, h1v, h2v, h3v);
            *(float4*)&h0[(size_t)node * HID + cx * 4] = hv;
        }
        float vd = h0v + h1v + h2v + h3v;
        float vw = h0v * wpv.x + h1v * wpv.y + h2v * wpv.z + h3v * wpv.w;
        float vi = h0v * wiv.x + h1v * wiv.y + h2v * wiv.z + h3v * wiv.w;
        float vj = h0v * wjv.x + h1v * wjv.y + h2v * wjv.z + h3v * wjv.w;
        #pragma unroll
        for (int m = 1; m < 16; m <<= 1) {
            vd += __shfl_xor(vd, m);
            vw += __shfl_xor(vw, m);
            vi += __shfl_xor(vi, m);
            vj += __shfl_xor(vj, m);
        }
        if (cx == 0 && node < n) {
            delta[node] = vd; hwp[node] = vw; ai[node] = vi; aj[node] = vj;
        }
    }
}

// ---------------- CSR build ----------------
__global__ __launch_bounds__(256) void k_scan1(
    const int* __restrict__ deg, int* __restrict__ rowptr,
    int* __restrict__ bsum, int n)
{
    __shared__ int sdata[256];
    const int t = threadIdx.x;
    const int i0 = blockIdx.x * 1024 + t * 4;
    int v[4];
    #pragma unroll
    for (int j = 0; j < 4; ++j) v[j] = (i0 + j < n) ? deg[i0 + j] : 0;
    int ts = v[0] + v[1] + v[2] + v[3];
    sdata[t] = ts;
    __syncthreads();
    for (int off = 1; off < 256; off <<= 1) {
        int add = (t >= off) ? sdata[t - off] : 0;
        __syncthreads();
        sdata[t] += add;
        __syncthreads();
    }
    int excl = sdata[t] - ts;
    int run = excl;
    #pragma unroll
    for (int j = 0; j < 4; ++j) {
        if (i0 + j < n) rowptr[i0 + j] = run;
        run += v[j];
    }
    if (t == 255) bsum[blockIdx.x] = sdata[255];
}

__global__ __launch_bounds__(128) void k_scan2(int* __restrict__ bsum, int B)
{
    __shared__ int sdata[128];
    const int t = threadIdx.x;
    int v = (t < B) ? bsum[t] : 0;
    sdata[t] = v;
    __syncthreads();
    for (int off = 1; off < 128; off <<= 1) {
        int add = (t >= off) ? sdata[t - off] : 0;
        __syncthreads();
        sdata[t] += add;
        __syncthreads();
    }
    if (t < B) bsum[t] = sdata[t] - v;
}

__global__ __launch_bounds__(256) void k_scan3(
    int* __restrict__ rowptr, int* __restrict__ cursor,
    const int* __restrict__ bsum, int n, int E)
{
    const int t = threadIdx.x;
    const int i0 = blockIdx.x * 1024 + t * 4;
    const int add = bsum[blockIdx.x];
    #pragma unroll
    for (int j = 0; j < 4; ++j) {
        int i = i0 + j;
        if (i < n) {
            int r = rowptr[i] + add;
            rowptr[i] = r;
            cursor[i] = r;
        }
    }
    if (blockIdx.x == 0 && t == 0) rowptr[n] = E;
}

// partitioned place: block handles node range [part*psize, ..+psize)
__global__ __launch_bounds__(256) void k_place(
    const int* __restrict__ dst, int* __restrict__ cursor,
    int* __restrict__ csr_eid, int E, int psize)
{
    const int part = blockIdx.x & 7;
    const int lo   = part * psize;
    const int hi   = lo + psize;
    int e = (blockIdx.x >> 3) * DCHUNK + threadIdx.x;
    #pragma unroll
    for (int it = 0; it < DCHUNK / 256; ++it, e += 256) {
        if (e < E) {
            int d = dst[e];
            if (d >= lo && d < hi) {
                int slot = atomicAdd(cursor + d, 1);
                csr_eid[slot] = e;
            }
        }
    }
}

// sort each row by edge id ascending (reference segment order, deterministic);
// materialize csr_src = src[eid].
__global__ __launch_bounds__(256) void k_sortrow(
    const int* __restrict__ rowptr, int* __restrict__ csr_eid,
    const int* __restrict__ src, int* __restrict__ csr_src, int n)
{
    int i = blockIdx.x * 256 + threadIdx.x;
    if (i >= n) return;
    const int p0 = rowptr[i], p1 = rowptr[i + 1];
    for (int a = p0 + 1; a < p1; ++a) {
        int key = csr_eid[a];
        int b = a - 1;
        while (b >= p0 && csr_eid[b] > key) {
            csr_eid[b + 1] = csr_eid[b];
            --b;
        }
        csr_eid[b + 1] = key;
    }
    for (int p = p0; p < p1; ++p) csr_src[p] = src[csr_eid[p]];
}

// ---------------- Attention prep ----------------
__global__ __launch_bounds__(256) void k_neigh_pi(
    const int* __restrict__ rowptr, const int* __restrict__ csr_src,
    const float* __restrict__ delta, const float* __restrict__ hwp,
    float* __restrict__ pi, int n)
{
    int i = blockIdx.x * 256 + threadIdx.x;
    if (i >= n) return;
    int p0 = rowptr[i], p1 = rowptr[i + 1];
    float s = 0.f;
    for (int p = p0; p < p1; ++p) s += delta[csr_src[p]];
    float v = hwp[i] + s;
    pi[i] = 1.f / (1.f + expf(-v));
}

__global__ __launch_bounds__(256) void k_att(
    const int* __restrict__ rowptr, const int* __restrict__ csr_src,
    const float* __restrict__ ai, const float* __restrict__ aj,
    const float* __restrict__ pi, const float* __restrict__ attw,
    const float* __restrict__ attb,
    float* __restrict__ alpha_csr, int n)
{
    int i = blockIdx.x * 256 + threadIdx.x;
    if (i >= n) return;
    const float wpe = attw[2 * HID];
    const float ab  = attb[0];
    int p0 = rowptr[i], p1 = rowptr[i + 1];
    float aid = ai[i];
    float den = 0.f;
    for (int p = p0; p < p1; ++p) {
        int s = csr_src[p];
        float v = aid + aj[s] + pi[s] * wpe + ab;
        v = v > 0.f ? v : 0.2f * v;
        float ev = expf(v);
        alpha_csr[p] = ev;
        den += ev;
    }
    float inv = 1.f / (den + 1e-16f);
    for (int p = p0; p < p1; ++p) alpha_csr[p] *= inv;
}

// ---------------- GEMM 64x64 (R4 exact) ----------------
__global__ __launch_bounds__(256) void k_gemm64(
    const float* __restrict__ hin, const float* __restrict__ W,
    const float* __restrict__ b, float* __restrict__ hout, int n, int relu_in)
{
    __shared__ float xs[64 * 68];
    __shared__ float Ws[HID * HID];
    const int t = threadIdx.x;
    const int node0 = blockIdx.x * 64;

    #pragma unroll
    for (int p = 0; p < 4; ++p) {
        int c = t + p * 256;
        *(float4*)&Ws[c * 4] = *(const float4*)&W[c * 4];
    }
    #pragma unroll
    for (int p = 0; p < 4; ++p) {
        int c = t + p * 256;
        int row = c >> 4;
        int col = (c & 15) * 4;
        float4 v = make_float4(0.f, 0.f, 0.f, 0.f);
        if (node0 + row < n) v = *(const float4*)&hin[(size_t)(node0 + row) * HID + col];
        if (relu_in) {
            v.x = fmaxf(v.x, 0.f); v.y = fmaxf(v.y, 0.f);
            v.z = fmaxf(v.z, 0.f); v.w = fmaxf(v.w, 0.f);
        }
        *(float4*)&xs[row * 68 + col] = v;
    }
    __syncthreads();

    const int cx = t & 15;
    const int ny = t >> 4;
    float acc[4][4];
    const float4 bv = *(const float4*)&b[cx * 4];
    #pragma unroll
    for (int i = 0; i < 4; ++i) {
        acc[i][0] = bv.x; acc[i][1] = bv.y; acc[i][2] = bv.z; acc[i][3] = bv.w;
    }

    #pragma unroll 4
    for (int k4 = 0; k4 < 16; ++k4) {
        float4 xv[4];
        #pragma unroll
        for (int i = 0; i < 4; ++i)
            xv[i] = *(const float4*)&xs[(i * 16 + ny) * 68 + k4 * 4];
        #pragma unroll
        for (int kk = 0; kk < 4; ++kk) {
            float4 w = *(const float4*)&Ws[(k4 * 4 + kk) * HID + cx * 4];
            #pragma unroll
            for (int i = 0; i < 4; ++i) {
                float xval = reinterpret_cast<const float*>(&xv[i])[kk];
                acc[i][0] = fmaf(xval, w.x, acc[i][0]);
                acc[i][1] = fmaf(xval, w.y, acc[i][1]);
                acc[i][2] = fmaf(xval, w.z, acc[i][2]);
                acc[i][3] = fmaf(xval, w.w, acc[i][3]);
            }
        }
    }

    #pragma unroll
    for (int i = 0; i < 4; ++i) {
        const int node = node0 + i * 16 + ny;
        if (node < n) {
            float4 hv = make_float4(acc[i][0], acc[i][1], acc[i][2], acc[i][3]);
            *(float4*)&hout[(size_t)node * HID + cx * 4] = hv;
        }
    }
}

// ---------------- Gather (R4 exact): out[d] = Sum alpha * hl[src] ---------
__global__ __launch_bounds__(256) void k_gather(
    const int* __restrict__ rowptr, const int* __restrict__ csr_src,
    const float* __restrict__ alpha_csr, const float* __restrict__ hl,
    float* __restrict__ out, int n)
{
    const int wave = threadIdx.x >> 6;
    const int lane = threadIdx.x & 63;
    const int g    = lane >> 4;
    const int q    = lane & 15;
    const int node = blockIdx.x * 4 + wave;
    if (node >= n) return;

    const int p0 = rowptr[node], p1 = rowptr[node + 1];
    float4 acc = make_float4(0.f, 0.f, 0.f, 0.f);

    for (int base = p0; base < p1; base += 64) {
        int m = p1 - base; if (m > 64) m = 64;
        float a_l = 0.f; int s_l = 0;
        if (lane < m) { a_l = alpha_csr[base + lane]; s_l = csr_src[base + lane]; }
        for (int j = 0; j < m; j += 4) {
            const int e = j + g;
            float a = __shfl(a_l, e);
            int   s = __shfl(s_l, e);
            if (e < m) {
                float4 v = *(const float4*)&hl[(size_t)s * HID + q * 4];
                acc.x = fmaf(a, v.x, acc.x);
                acc.y = fmaf(a, v.y, acc.y);
                acc.z = fmaf(a, v.z, acc.z);
                acc.w = fmaf(a, v.w, acc.w);
            }
        }
    }
    #pragma unroll
    for (int m2 = 16; m2 <= 32; m2 <<= 1) {
        acc.x += __shfl_xor(acc.x, m2);
        acc.y += __shfl_xor(acc.y, m2);
        acc.z += __shfl_xor(acc.z, m2);
        acc.w += __shfl_xor(acc.w, m2);
    }
    if (g == 0)
        *(float4*)&out[(size_t)node * HID + q * 4] = acc;
}

// ---------------- Output GEMM 64x40 (R4 exact) ----------------
__global__ __launch_bounds__(256) void k_out_gemm(
    const float* __restrict__ hin, const float* __restrict__ W,
    const float* __restrict__ b, float* __restrict__ out, int n)
{
    __shared__ float xs[128 * 68];
    __shared__ float Ws[HID * 40];
    const int t = threadIdx.x;
    const int node0 = blockIdx.x * 128;

    #pragma unroll
    for (int p = 0; p < 3; ++p) {
        int c = t + p * 256;
        if (c < 640) *(float4*)&Ws[c * 4] = *(const float4*)&W[c * 4];
    }
    #pragma unroll
    for (int p = 0; p < 8; ++p) {
        int c = t + p * 256;
        int row = c >> 4;
        int col = (c & 15) * 4;
        float4 v = make_float4(0.f, 0.f, 0.f, 0.f);
        if (node0 + row < n) v = *(const float4*)&hin[(size_t)(node0 + row) * HID + col];
        v.x = fmaxf(v.x, 0.f); v.y = fmaxf(v.y, 0.f);
        v.z = fmaxf(v.z, 0.f); v.w = fmaxf(v.w, 0.f);
        *(float4*)&xs[row * 68 + col] = v;
    }
    __syncthreads();

    const int cx = t & 7;
    const int ny = t >> 3;
    float acc[4][5];
    #pragma unroll
    for (int j = 0; j < 5; ++j) {
        float bj = b[5 * cx + j];
        #pragma unroll
        for (int i = 0; i < 4; ++i) acc[i][j] = bj;
    }

    #pragma unroll 4
    for (int k4 = 0; k4 < 16; ++k4) {
        float4 xv[4];
        #pragma unroll
        for (int i = 0; i < 4; ++i)
            xv[i] = *(const float4*)&xs[(i * 32 + ny) * 68 + k4 * 4];
        #pragma unroll
        for (int kk = 0; kk < 4; ++kk) {
            int k = k4 * 4 + kk;
            float w[5];
            #pragma unroll
            for (int j = 0; j < 5; ++j) w[j] = Ws[k * 40 + 5 * cx + j];
            #pragma unroll
            for (int i = 0; i < 4; ++i) {
                float xval = reinterpret_cast<const float*>(&xv[i])[kk];
                #pragma unroll
                for (int j = 0; j < 5; ++j)
                    acc[i][j] = fmaf(xval, w[j], acc[i][j]);
            }
        }
    }

    #pragma unroll
    for (int i = 0; i < 4; ++i) {
        const int node = node0 + i * 32 + ny;
        if (node < n) {
            #pragma unroll
            for (int j = 0; j < 5; ++j)
                out[(size_t)node * 40 + 5 * cx + j] = acc[i][j];
        }
    }
}

extern "C" void kernel_launch(void* const* d_in, const int* in_sizes, int n_in,
                              void* d_out, int out_size, void* d_ws, size_t ws_size,
                              hipStream_t stream) {
    const float* x    = (const float*)d_in[0];
    const int*   ei   = (const int*)d_in[1];
    const float* Win  = (const float*)d_in[2];
    const float* bin  = (const float*)d_in[3];
    const float* wp   = (const float*)d_in[4];
    const float* attw = (const float*)d_in[5];
    const float* attb = (const float*)d_in[6];
    const float* Wout = (const float*)d_in[7];
    const float* bout = (const float*)d_in[8];
    const float* W0   = (const float*)d_in[9];
    const float* b0   = (const float*)d_in[10];
    const float* W1   = (const float*)d_in[11];
    const float* b1   = (const float*)d_in[12];
    const float* W2   = (const float*)d_in[13];
    const float* b2   = (const float*)d_in[14];

    const int N = in_sizes[0] / INC;
    const int E = in_sizes[1] / 2;
    const int* src = ei;
    const int* dst = ei + E;
    float* out = (float*)d_out;

    char* ws = (char*)d_ws;
    size_t off = 0;
    auto alloc = [&](size_t bytes) -> void* {
        void* p = ws + off;
        off = (off + bytes + 255) & ~(size_t)255;
        return p;
    };
    float* A       = (float*)alloc((size_t)N * HID * 4);
    float* Bf      = (float*)alloc((size_t)N * HID * 4);
    float* C       = (float*)alloc((size_t)N * HID * 4);
    float* delta   = (float*)alloc((size_t)N * 4);
    float* hwp     = (float*)alloc((size_t)N * 4);
    float* ai      = (float*)alloc((size_t)N * 4);
    float* aj      = (float*)alloc((size_t)N * 4);
    float* pi      = (float*)alloc((size_t)N * 4);
    int*   deg     = (int*)alloc((size_t)N * 4);
    int*   rowptr  = (int*)alloc((size_t)(N + 1) * 4);
    int*   cursor  = (int*)alloc((size_t)N * 4);
    int*   bsum    = (int*)alloc(256 * 4);
    int*   csr_eid = (int*)alloc((size_t)E * 4);
    int*   csr_src = (int*)alloc((size_t)E * 4);
    float* alpha   = (float*)alloc((size_t)E * 4);

    const int tileBlocks64  = (N + 63) / 64;          // 1563
    const int tileBlocks128 = (N + 127) / 128;
    const int nodeBlocks256 = (N + 255) / 256;
    const int nodeBlocksW   = (N + 3) / 4;
    const int scanBlocks    = (N + 1023) / 1024;

    const int psize     = (N + 7) / 8;                // 12500 nodes per XCD
    const int nchunks   = (E + DCHUNK - 1) / DCHUNK;  // 391
    const int partBlocks = 8 * nchunks;               // 3128

    const int NG = tileBlocks64;
    const int fusedBlocks = NG + partBlocks;

    hipMemsetAsync(deg, 0, (size_t)N * 4, stream);

    // ---- in_gemm || partitioned degree count ----
    k_ingemm_deg<<<fusedBlocks, 256, 0, stream>>>(
        x, Win, bin, wp, attw, A, delta, hwp, ai, aj, N, dst, deg, E, NG, psize);

    // ---- CSR build (deterministic sorted rows) ----
    k_scan1<<<scanBlocks, 256, 0, stream>>>(deg, rowptr, bsum, N);
    k_scan2<<<1, 128, 0, stream>>>(bsum, scanBlocks);
    k_scan3<<<scanBlocks, 256, 0, stream>>>(rowptr, cursor, bsum, N, E);
    k_place<<<partBlocks, 256, 0, stream>>>(dst, cursor, csr_eid, E, psize);
    k_sortrow<<<nodeBlocks256, 256, 0, stream>>>(rowptr, csr_eid, src, csr_src, N);

    // ---- attention ----
    k_neigh_pi<<<nodeBlocks256, 256, 0, stream>>>(rowptr, csr_src, delta, hwp, pi, N);
    k_att<<<nodeBlocks256, 256, 0, stream>>>(rowptr, csr_src, ai, aj, pi,
                                             attw, attb, alpha, N);

    // ---- layers (R4 exact) ----
    k_gemm64<<<tileBlocks64, 256, 0, stream>>>(A, W0, b0, Bf, N, 0);
    k_gather<<<nodeBlocksW, 256, 0, stream>>>(rowptr, csr_src, alpha, Bf, C, N);

    k_gemm64<<<tileBlocks64, 256, 0, stream>>>(C, W1, b1, A, N, 1);
    k_gather<<<nodeBlocksW, 256, 0, stream>>>(rowptr, csr_src, alpha, A, Bf, N);

    k_gemm64<<<tileBlocks64, 256, 0, stream>>>(Bf, W2, b2, C, N, 1);
    k_gather<<<nodeBlocksW, 256, 0, stream>>>(rowptr, csr_src, alpha, C, A, N);

    k_out_gemm<<<tileBlocks128, 256, 0, stream>>>(A, Wout, bout, out, N);
}